// Round 1
// baseline (46.877 us; speedup 1.0000x reference)
//
#include <hip/hip_runtime.h>
#include <math.h>

// Problem constants (from reference): B=8, S=4096, D=1024, fp32 in/out.
#define B_   8
#define S_   4096
#define D_   1024
#define RPW  16                 // rows (seq positions) per wave
#define NPB  (S_ / RPW)         // 256 partials per batch
#define NP   (B_ * NPB)         // 2048 partials total
#define G1   16                 // combine1 groups per batch
#define PPG  (NPB / G1)         // 16 partials per combine1 block

// ws layout (float offsets)
#define PM_OFF    0                       // [NP]
#define PL_OFF    (PM_OFF + NP)           // [NP]
#define L2_OFF    (PL_OFF + NP)           // [B_*G1]
#define PACC_OFF  8192                    // [NP * D_]   (16B aligned)
#define ACC2_OFF  (PACC_OFF + NP * D_)    // [B_*G1*D_]

// ---------------------------------------------------------------------------
// Pass 1: one pass over data. Each wave handles 16 consecutive rows of one b.
// Lane owns columns {j*256 + lane*4 .. +3} for j=0..3 (as float4), so the
// row dot-product is 16 thread-local FMAs + a 64-lane shfl_xor butterfly.
// Online softmax (m, l, acc) per wave; partials written to ws.
// ---------------------------------------------------------------------------
__global__ __launch_bounds__(256) void attn_pass1(
    const float* __restrict__ data, const float* __restrict__ crit,
    float* __restrict__ pm, float* __restrict__ pl, float* __restrict__ pacc)
{
    const int lane = threadIdx.x & 63;
    const int gw   = blockIdx.x * 4 + (threadIdx.x >> 6);  // global wave id, 0..NP-1
    const int b    = gw >> 8;                               // / NPB (=256)
    const int pi   = gw & 255;                              // % NPB
    const int s0   = pi * RPW;

    // crit fragment for this lane's 16 columns
    const float4* c4p = reinterpret_cast<const float4*>(crit + (size_t)b * D_);
    float4 cc[4];
    cc[0] = c4p[0 * 64 + lane];
    cc[1] = c4p[1 * 64 + lane];
    cc[2] = c4p[2 * 64 + lane];
    cc[3] = c4p[3 * 64 + lane];

    const float4* dp = reinterpret_cast<const float4*>(data)
                     + (size_t)(b * S_ + s0) * (D_ / 4);

    float4 a0 = {0,0,0,0}, a1 = {0,0,0,0}, a2 = {0,0,0,0}, a3 = {0,0,0,0};
    float m = -INFINITY, l = 0.f;

    // 4 groups of 4 rows. unroll 2: enough load batching for prefetch
    // without hoisting all 64 dwordx4 (VGPR blowup).
    #pragma unroll 2
    for (int g = 0; g < RPW / 4; ++g) {
        float4 v[4][4];
        #pragma unroll
        for (int r = 0; r < 4; ++r) {
            const float4* rp = dp + (size_t)(g * 4 + r) * (D_ / 4);
            v[r][0] = rp[0 * 64 + lane];
            v[r][1] = rp[1 * 64 + lane];
            v[r][2] = rp[2 * 64 + lane];
            v[r][3] = rp[3 * 64 + lane];
        }

        float sc[4];
        #pragma unroll
        for (int r = 0; r < 4; ++r) {
            float p = 0.f;
            #pragma unroll
            for (int j = 0; j < 4; ++j) {
                p = fmaf(v[r][j].x, cc[j].x, p);
                p = fmaf(v[r][j].y, cc[j].y, p);
                p = fmaf(v[r][j].z, cc[j].z, p);
                p = fmaf(v[r][j].w, cc[j].w, p);
            }
            sc[r] = p;
        }

        // 4 independent 64-lane butterfly reductions (pipelined)
        #pragma unroll
        for (int off = 32; off >= 1; off >>= 1) {
            sc[0] += __shfl_xor(sc[0], off, 64);
            sc[1] += __shfl_xor(sc[1], off, 64);
            sc[2] += __shfl_xor(sc[2], off, 64);
            sc[3] += __shfl_xor(sc[3], off, 64);
        }

        const float gm = fmaxf(fmaxf(sc[0], sc[1]), fmaxf(sc[2], sc[3]));
        const float mn = fmaxf(m, gm);
        const float scale = __expf(m - mn);       // exp(-inf)=0 on first group
        const float p0 = __expf(sc[0] - mn);
        const float p1 = __expf(sc[1] - mn);
        const float p2 = __expf(sc[2] - mn);
        const float p3 = __expf(sc[3] - mn);
        l = fmaf(l, scale, p0 + p1 + p2 + p3);

        #define UPD1(A, J, F)                                                     \
            A.F = fmaf(A.F, scale,                                                \
                  fmaf(p0, v[0][J].F, fmaf(p1, v[1][J].F,                         \
                  fmaf(p2, v[2][J].F, p3 * v[3][J].F))));
        #define UPD(A, J) UPD1(A, J, x) UPD1(A, J, y) UPD1(A, J, z) UPD1(A, J, w)
        UPD(a0, 0) UPD(a1, 1) UPD(a2, 2) UPD(a3, 3)
        #undef UPD
        #undef UPD1

        m = mn;
    }

    float4* po = reinterpret_cast<float4*>(pacc) + (size_t)gw * (D_ / 4);
    po[0 * 64 + lane] = a0;
    po[1 * 64 + lane] = a1;
    po[2 * 64 + lane] = a2;
    po[3 * 64 + lane] = a3;
    if (lane == 0) { pm[gw] = m; pl[gw] = l; }
}

// ---------------------------------------------------------------------------
// Combine level 1: block (g, b) merges partials c = g*PPG .. g*PPG+PPG-1 of
// batch b under the global max m* (computed redundantly from the tiny pm[]).
// ---------------------------------------------------------------------------
__global__ __launch_bounds__(256) void attn_combine1(
    const float* __restrict__ pm, const float* __restrict__ pl,
    const float* __restrict__ pacc, float* __restrict__ acc2,
    float* __restrict__ l2)
{
    const int b = blockIdx.y;
    const int g = blockIdx.x;
    const int t = threadIdx.x;

    float mstar = -INFINITY;
    #pragma unroll 8
    for (int c = 0; c < NPB; ++c) mstar = fmaxf(mstar, pm[b * NPB + c]);

    float4 s = {0,0,0,0};
    float  sl = 0.f;
    #pragma unroll
    for (int k = 0; k < PPG; ++k) {
        const int c = b * NPB + g * PPG + k;
        const float f = __expf(pm[c] - mstar);
        const float4 v =
            reinterpret_cast<const float4*>(pacc)[(size_t)c * (D_ / 4) + t];
        s.x = fmaf(f, v.x, s.x);
        s.y = fmaf(f, v.y, s.y);
        s.z = fmaf(f, v.z, s.z);
        s.w = fmaf(f, v.w, s.w);
        sl  = fmaf(f, pl[c], sl);
    }
    reinterpret_cast<float4*>(acc2)[(size_t)(b * G1 + g) * (D_ / 4) + t] = s;
    if (t == 0) l2[b * G1 + g] = sl;
}

// ---------------------------------------------------------------------------
// Combine level 2: final sum over G1 groups, divide by denominator, store out.
// ---------------------------------------------------------------------------
__global__ __launch_bounds__(256) void attn_combine2(
    const float* __restrict__ acc2, const float* __restrict__ l2,
    float* __restrict__ out)
{
    const int b = blockIdx.x;
    const int t = threadIdx.x;

    float L = 0.f;
    #pragma unroll
    for (int g = 0; g < G1; ++g) L += l2[b * G1 + g];

    float4 s = {0,0,0,0};
    #pragma unroll
    for (int g = 0; g < G1; ++g) {
        const float4 v =
            reinterpret_cast<const float4*>(acc2)[(size_t)(b * G1 + g) * (D_ / 4) + t];
        s.x += v.x; s.y += v.y; s.z += v.z; s.w += v.w;
    }
    const float inv = 1.f / L;
    float4 o = { s.x * inv, s.y * inv, s.z * inv, s.w * inv };
    reinterpret_cast<float4*>(out)[(size_t)b * (D_ / 4) + t] = o;
}

extern "C" void kernel_launch(void* const* d_in, const int* in_sizes, int n_in,
                              void* d_out, int out_size, void* d_ws, size_t ws_size,
                              hipStream_t stream)
{
    const float* data = (const float*)d_in[0];   // [B, S, D]
    const float* crit = (const float*)d_in[1];   // [B, D]
    float* ws   = (float*)d_ws;
    float* pm   = ws + PM_OFF;
    float* pl   = ws + PL_OFF;
    float* l2   = ws + L2_OFF;
    float* pacc = ws + PACC_OFF;
    float* acc2 = ws + ACC2_OFF;
    float* out  = (float*)d_out;

    attn_pass1   <<<NP / 4, 256, 0, stream>>>(data, crit, pm, pl, pacc);
    attn_combine1<<<dim3(G1, B_), 256, 0, stream>>>(pm, pl, pacc, acc2, l2);
    attn_combine2<<<B_, 256, 0, stream>>>(acc2, l2, out);
}